// Round 10
// baseline (1264.187 us; speedup 1.0000x reference)
//
#include <hip/hip_runtime.h>
#include <hip/hip_bf16.h>
#include <math.h>

#define TOKENS 8192
#define HDIM 1152
#define SEQ 2048
#define NHEADS 12
#define HEADD 96
#define NMEM 4
#define MEMD 128
#define FINNER 4608

typedef __hip_bfloat16 bf16;
typedef __attribute__((ext_vector_type(8))) short short8;
typedef __attribute__((ext_vector_type(4))) float floatx4;

__device__ __constant__ int g_hd_dil[NHEADS * 3] = {
    1, 2, 4,   1, 1, 1,    4, 8, 16,   8, 16, 32,
    32, 64, 128, 64, 128, 256, 256, 512, 1024, 1, 100, 200,
    1, 500, 1000, 1, 1024, 2048, 3, 9, 27, 5, 25, 125};

__device__ inline float sigm(float x) { return 1.0f / (1.0f + __expf(-x)); }
__device__ inline float gelu_exact(float x) {
  return 0.5f * x * (1.0f + erff(x * 0.70710678118654752f));
}
__device__ inline float wred(float v) {
#pragma unroll
  for (int o = 32; o > 0; o >>= 1) v += __shfl_down(v, o);
  return v;
}
// async global->LDS, 16B per lane; LDS dest wave-uniform base + lane*16
__device__ inline void gl_lds16(const bf16* g, bf16* l) {
  __builtin_amdgcn_global_load_lds(
      (const __attribute__((address_space(1))) unsigned int*)g,
      (__attribute__((address_space(3))) unsigned int*)l, 16, 0, 0);
}

// ---------------- transpose f32 [K,N] -> bf16 [N,K] ----------------
__global__ __launch_bounds__(256) void k_transpose_bf16(
    const float* __restrict__ W, bf16* __restrict__ WT, int K, int N) {
  __shared__ float t[32][33];
  int k0 = blockIdx.y * 32, n0 = blockIdx.x * 32;
  int tx = threadIdx.x & 31, ty = threadIdx.x >> 5;
#pragma unroll
  for (int i = 0; i < 32; i += 8)
    t[ty + i][tx] = W[(size_t)(k0 + ty + i) * N + (n0 + tx)];
  __syncthreads();
#pragma unroll
  for (int i = 0; i < 32; i += 8)
    WT[(size_t)(n0 + ty + i) * K + (k0 + tx)] = __float2bfloat16(t[tx][ty + i]);
}

// ---- 16-col-interleaved pair transpose ----
// WT row r <- W col src(r) = (r>>5)*16 + (r&15) + ((r>>4)&1)*half.
// Within a GEMM wave, nt-even fragments hold a-cols and nt-odd the matching
// g-cols for the SAME lane -> shfl-free pair-GLU epilogue.
__global__ __launch_bounds__(256) void k_transpose_pair(
    const float* __restrict__ W, bf16* __restrict__ WT, int K, int N) {
  __shared__ float t[32][33];
  int half = N >> 1;
  int k0 = blockIdx.y * 32, n0 = blockIdx.x * 32;
  int tx = threadIdx.x & 31, ty = threadIdx.x >> 5;
  // src col for output row n0+tx (n0%32==0): identical formula to before
  int c = (tx < 16) ? (n0 / 2 + tx) : (half + n0 / 2 + tx - 16);
#pragma unroll
  for (int i = 0; i < 32; i += 8)
    t[ty + i][tx] = W[(size_t)(k0 + ty + i) * N + c];
  __syncthreads();
#pragma unroll
  for (int i = 0; i < 32; i += 8) {
    int r = ty + i;
    WT[(size_t)(n0 + r) * K + (k0 + tx)] = __float2bfloat16(t[tx][r]);
  }
}

// ------- rmsnorm + scalar gate, wave-per-token (4 tokens/block) -------
__global__ __launch_bounds__(256) void k_rms_gate(
    const float* __restrict__ x, const float* __restrict__ nw,
    const float* __restrict__ gw, const float* __restrict__ gb,
    bf16* __restrict__ outb, float* __restrict__ gout,
    const float* __restrict__ rw, const float* __restrict__ rb,
    float* __restrict__ hwout) {
  int wave = threadIdx.x >> 6, lane = threadIdx.x & 63;
  int tok = blockIdx.x * 4 + wave;
  const float* row = x + (size_t)tok * HDIM;
  float2 a[9];
  float s2 = 0.f, gd = 0.f;
#pragma unroll
  for (int p = 0; p < 9; ++p) {
    int i2 = lane + 64 * p;
    a[p] = *reinterpret_cast<const float2*>(&row[i2 * 2]);
    float2 g2 = *reinterpret_cast<const float2*>(&gw[i2 * 2]);
    s2 += a[p].x * a[p].x + a[p].y * a[p].y;
    gd += a[p].x * g2.x + a[p].y * g2.y;
  }
  s2 = wred(s2);
  gd = wred(gd);
  if (lane == 0) gout[tok] = sigm(gd + gb[0]);
  s2 = __shfl(s2, 0);
  float rn = 1.0f / sqrtf(s2 / (float)HDIM + 1e-6f);
  float racc[NHEADS];
#pragma unroll
  for (int o = 0; o < NHEADS; ++o) racc[o] = 0.f;
#pragma unroll
  for (int p = 0; p < 9; ++p) {
    int i2 = lane + 64 * p;
    float2 w2 = *reinterpret_cast<const float2*>(&nw[i2 * 2]);
    float nx = a[p].x * rn * w2.x;
    float ny = a[p].y * rn * w2.y;
    __hip_bfloat162 pr;
    pr.x = __float2bfloat16(nx);
    pr.y = __float2bfloat16(ny);
    *reinterpret_cast<__hip_bfloat162*>(&outb[(size_t)tok * HDIM + i2 * 2]) = pr;
    if (hwout) {
      // rw rows are 12 floats (48B, 16B-aligned): 3 float4 per row, 2 rows.
      const float4* rp4 =
          reinterpret_cast<const float4*>(&rw[(size_t)(i2 * 2) * NHEADS]);
      float4 r0 = rp4[0], r1 = rp4[1], r2 = rp4[2];
      float4 r3 = rp4[3], r4 = rp4[4], r5 = rp4[5];
      racc[0] += nx * r0.x + ny * r3.x;
      racc[1] += nx * r0.y + ny * r3.y;
      racc[2] += nx * r0.z + ny * r3.z;
      racc[3] += nx * r0.w + ny * r3.w;
      racc[4] += nx * r1.x + ny * r4.x;
      racc[5] += nx * r1.y + ny * r4.y;
      racc[6] += nx * r1.z + ny * r4.z;
      racc[7] += nx * r1.w + ny * r4.w;
      racc[8] += nx * r2.x + ny * r5.x;
      racc[9] += nx * r2.y + ny * r5.y;
      racc[10] += nx * r2.z + ny * r5.z;
      racc[11] += nx * r2.w + ny * r5.w;
    }
  }
  if (hwout) {
#pragma unroll
    for (int o = 0; o < NHEADS; ++o) {
      float r = wred(racc[o]);
      if (lane == 0) hwout[(size_t)tok * NHEADS + o] = sigm(r + rb[o]);
    }
  }
}

// ---------------- fused conv stack: 6 stages, single LDS buffer ----------------
// Channel-pair per thread: float2 LDS reads/writes (halves LDS instr count).
#define CS_T 256
#define CS_HALO 189
#define CS_ROWS 445
#define CS_J2 14
__global__ __launch_bounds__(256) void k_convstack(
    const bf16* __restrict__ hin, bf16* __restrict__ outb,
    const float* __restrict__ cw, const float* __restrict__ cb) {
  __shared__ float cur[CS_ROWS * 16];
  int bx = blockIdx.x;
  int cs = bx % 72;
  int tile = (bx / 72) & 7;
  int b = bx / 576;
  int c0 = cs * 16;
  int S0 = tile * CS_T;
  int tid = threadIdx.x;
  int c4 = tid & 7, pg = tid >> 3;  // channel pair 2*c4, row-group of 32
  for (int i = tid; i < CS_ROWS * 8; i += 256) {
    int p = i >> 3, cc2 = (i & 7) * 2;
    int sg = S0 - CS_HALO + p;
    if (sg >= 0) {
      unsigned int u = *reinterpret_cast<const unsigned int*>(
          &hin[((size_t)(b * SEQ + sg)) * HDIM + c0 + cc2]);
      cur[p * 16 + cc2] = __uint_as_float(u << 16);
      cur[p * 16 + cc2 + 1] = __uint_as_float(u & 0xffff0000u);
    } else {
      cur[p * 16 + cc2] = 0.f;
      cur[p * 16 + cc2 + 1] = 0.f;
    }
  }
  const int dil[6] = {1, 2, 4, 8, 16, 32};
  const int Nk[6] = {3, 9, 21, 45, 93, 189};
  float2 nv[CS_J2];
#pragma unroll
  for (int k = 0; k < 6; ++k) {
    int dd = dil[k] * 16;
    const float4* wp = reinterpret_cast<const float4*>(
        &cw[((size_t)k * HDIM + c0 + c4 * 2) * 4]);
    float4 wA = wp[0], wB = wp[1];
    float2 bb = *reinterpret_cast<const float2*>(&cb[(size_t)k * HDIM + c0 + c4 * 2]);
    __syncthreads();
#pragma unroll
    for (int j = 0; j < CS_J2; ++j) {
      int p = pg + 32 * j;
      if (p >= Nk[k] && p < CS_ROWS) {
        int i = p * 16 + c4 * 2;
        float2 t3 = *reinterpret_cast<const float2*>(&cur[i - 3 * dd]);
        float2 t2 = *reinterpret_cast<const float2*>(&cur[i - 2 * dd]);
        float2 t1 = *reinterpret_cast<const float2*>(&cur[i - dd]);
        float2 t0 = *reinterpret_cast<const float2*>(&cur[i]);
        float acc0 = bb.x + wA.x * t3.x + wA.y * t2.x + wA.z * t1.x + wA.w * t0.x;
        float acc1 = bb.y + wB.x * t3.y + wB.y * t2.y + wB.z * t1.y + wB.w * t0.y;
        int sg = S0 - CS_HALO + p;
        if (sg >= 0) {
          nv[j].x = t0.x + gelu_exact(acc0);
          nv[j].y = t0.y + gelu_exact(acc1);
        } else {
          nv[j].x = 0.f;
          nv[j].y = 0.f;
        }
      }
    }
    __syncthreads();
#pragma unroll
    for (int j = 0; j < CS_J2; ++j) {
      int p = pg + 32 * j;
      if (p >= Nk[k] && p < CS_ROWS)
        *reinterpret_cast<float2*>(&cur[p * 16 + c4 * 2]) = nv[j];
    }
  }
  __syncthreads();
  for (int r = pg; r < CS_T; r += 32) {
    float2 v2 = *reinterpret_cast<const float2*>(&cur[(CS_HALO + r) * 16 + c4 * 2]);
    __hip_bfloat162 pr;
    pr.x = __float2bfloat16(v2.x);
    pr.y = __float2bfloat16(v2.y);
    *reinterpret_cast<__hip_bfloat162*>(
        &outb[((size_t)(b * SEQ + S0 + r)) * HDIM + c0 + c4 * 2]) = pr;
  }
}

// ---------------- per-head conv step j: h = h + dconv(h), float4 ----------------
__global__ __launch_bounds__(256) void k_headconv(
    const float* __restrict__ hin, float* __restrict__ hout,
    const float* __restrict__ hw_, const float* __restrict__ hb_, int j) {
  size_t idx4 = (size_t)blockIdx.x * 256 + threadIdx.x;
  if (idx4 >= (size_t)TOKENS * HDIM / 4) return;
  size_t idx = idx4 * 4;
  int c = (int)(idx % HDIM);
  int head = c / HEADD, hd = c % HEADD;
  size_t tok = idx / HDIM;
  int s = (int)(tok % SEQ);
  int d = g_hd_dil[head * 3 + j];
  const float4* wv = reinterpret_cast<const float4*>(
      hw_ + ((size_t)(head * 3 + j) * HEADD + hd) * 4);
  float4 w0 = wv[0], w1 = wv[1], w2 = wv[2], w3 = wv[3];
  float4 bb = *reinterpret_cast<const float4*>(
      &hb_[(size_t)(head * 3 + j) * HEADD + hd]);
  float av0 = bb.x, av1 = bb.y, av2 = bb.z, av3 = bb.w;
  float4 base = *reinterpret_cast<const float4*>(&hin[idx]);
#pragma unroll
  for (int jj = 0; jj < 4; ++jj) {
    int back = (3 - jj) * d;
    if (s - back >= 0) {
      float4 t = *reinterpret_cast<const float4*>(&hin[idx - (size_t)back * HDIM]);
      float a0 = (jj == 0) ? w0.x : (jj == 1) ? w0.y : (jj == 2) ? w0.z : w0.w;
      float a1 = (jj == 0) ? w1.x : (jj == 1) ? w1.y : (jj == 2) ? w1.z : w1.w;
      float a2 = (jj == 0) ? w2.x : (jj == 1) ? w2.y : (jj == 2) ? w2.z : w2.w;
      float a3 = (jj == 0) ? w3.x : (jj == 1) ? w3.y : (jj == 2) ? w3.z : w3.w;
      av0 += a0 * t.x;
      av1 += a1 * t.y;
      av2 += a2 * t.z;
      av3 += a3 * t.w;
    }
  }
  float4 o = {base.x + av0, base.y + av1, base.z + av2, base.w + av3};
  *reinterpret_cast<float4*>(&hout[idx]) = o;
}

// ---------------- GEMM: BK=64, global_load_lds staging, swizzled LDS ----------
// MODE 2: out = addin + gate[m]*(acc+bias)
// MODE 4: pair-GLU -> a*sigm(g) f32 (16-col-interleaved WT; shfl-free)
// MODE 5: pair-GLU -> bf16 (same)
// MODE 6: outb = bf16(addin * sigm(acc+bias))
template <int MODE>
__global__ __launch_bounds__(256) void k_gemm(
    const bf16* __restrict__ A, const bf16* __restrict__ BT,
    const float* __restrict__ bias, const float* __restrict__ gate,
    const float* addin, float* outf, bf16* outb, int M, int N, int K) {
  __shared__ bf16 As[128 * 64];
  __shared__ bf16 Bs[128 * 64];
  const int tid = threadIdx.x;
  const int m0 = blockIdx.y * 128, n0 = blockIdx.x * 128;
  const int wave = tid >> 6, lane = tid & 63;
  const int wm = (wave & 1) * 64, wn = (wave >> 1) * 64;
  const int l16 = lane & 15, kq = lane >> 4;
  const int srow = lane >> 3;
  const int schunk = ((lane & 7) - srow) & 7;
  const bf16* gA = A + (size_t)(m0 + wave * 32 + srow) * K + schunk * 8;
  const bf16* gB = BT + (size_t)(n0 + wave * 32 + srow) * K + schunk * 8;
  bf16* lA = &As[wave * 32 * 64];
  bf16* lB = &Bs[wave * 32 * 64];
  const size_t rstride = (size_t)8 * K;
  const int col0 = ((kq + l16) & 7) * 8;
  const int col1 = ((kq + 4 + l16) & 7) * 8;
  floatx4 acc[4][4];
  floatx4 zero = {0.f, 0.f, 0.f, 0.f};
#pragma unroll
  for (int i = 0; i < 4; ++i)
#pragma unroll
    for (int jj = 0; jj < 4; ++jj) acc[i][jj] = zero;

  for (int k0 = 0; k0 < K; k0 += 64) {
    __syncthreads();
#pragma unroll
    for (int i = 0; i < 4; ++i) {
      gl_lds16(gA + k0 + i * rstride, lA + i * 8 * 64);
      gl_lds16(gB + k0 + i * rstride, lB + i * 8 * 64);
    }
    __syncthreads();
#pragma unroll
    for (int ks = 0; ks < 2; ++ks) {
      const int col = ks ? col1 : col0;
      short8 af[4], bfr[4];
#pragma unroll
      for (int t = 0; t < 4; ++t) {
        af[t] = *reinterpret_cast<const short8*>(&As[(wm + t * 16 + l16) * 64 + col]);
        bfr[t] = *reinterpret_cast<const short8*>(&Bs[(wn + t * 16 + l16) * 64 + col]);
      }
#pragma unroll
      for (int mt = 0; mt < 4; ++mt)
#pragma unroll
        for (int nt = 0; nt < 4; ++nt)
          acc[mt][nt] = __builtin_amdgcn_mfma_f32_16x16x32_bf16(
              af[mt], bfr[nt], acc[mt][nt], 0, 0, 0);
    }
  }

  if (MODE == 4 || MODE == 5) {
    const int halfN = N >> 1;
    // nt even holds a, nt odd holds g for the SAME lane (16-col interleave).
#pragma unroll
    for (int mt = 0; mt < 4; ++mt) {
#pragma unroll
      for (int ntp = 0; ntp < 2; ++ntp) {
        int cc = ((n0 + wn) >> 1) + ntp * 16 + l16;
#pragma unroll
        for (int r = 0; r < 4; ++r) {
          float a = acc[mt][ntp * 2][r];
          float g = acc[mt][ntp * 2 + 1][r];
          int m = m0 + wm + mt * 16 + kq * 4 + r;
          float res = a * sigm(g);
          size_t o = (size_t)m * halfN + cc;
          if (MODE == 4) outf[o] = res;
          else outb[o] = __float2bfloat16(res);
        }
      }
    }
    return;
  }

#pragma unroll
  for (int mt = 0; mt < 4; ++mt) {
#pragma unroll
    for (int nt = 0; nt < 4; ++nt) {
      int n = n0 + wn + nt * 16 + l16;
      float bv = bias ? bias[n] : 0.f;
#pragma unroll
      for (int r = 0; r < 4; ++r) {
        int m = m0 + wm + mt * 16 + kq * 4 + r;
        float v = acc[mt][nt][r] + bv;
        size_t o = (size_t)m * N + n;
        if (MODE == 2) outf[o] = addin[o] + gate[m] * v;
        else if (MODE == 6) outb[o] = __float2bfloat16(addin[o] * sigm(v));
      }
    }
  }
}

// -------- memory q/kg/v/g projections: token-tiled, register-blocked --------
#define QT 16
#define QTP 20  // padded LDS stride
__global__ __launch_bounds__(256) void k_qkvg(
    const float* __restrict__ xh, const float* __restrict__ Wq,
    const float* __restrict__ Wk, const float* __restrict__ Wv,
    const float* __restrict__ gw, const float* __restrict__ gb,
    float* __restrict__ q, float* __restrict__ kg, float* __restrict__ v,
    float* __restrict__ gout) {
  __shared__ float xT[384 * QTP];  // xT[dd*QTP + t]
  __shared__ float gsh[QT][NMEM];
  int bx = blockIdx.x;
  int grp = bx & 1;
  int tile = bx >> 1;
  int t0 = tile * QT;
  int tid = threadIdx.x;
  for (int i = tid; i < 384 * QT; i += 256) {
    int t = i / 384, dd = i % 384;
    xT[dd * QTP + t] = xh[(size_t)(t0 + t) * HDIM + 6 * HEADD + dd];
  }
  __syncthreads();
  if (grp == 0) {
    if (tid < 64) {
      int t = tid >> 2, n = tid & 3;
      float a = gb[n];
      for (int d = 0; d < HEADD; ++d)
        a += xT[(n * HEADD + d) * QTP + t] * gw[n * HEADD + d];
      float s = sigm(a);
      gsh[t][n] = s;
      gout[(size_t)(t0 + t) * NMEM + n] = s;
    }
    __syncthreads();
  }
  int o = grp * 1024 + tid * 4;
  if (o >= 1280) return;
  float acc[4][QT];
#pragma unroll
  for (int e = 0; e < 4; ++e)
#pragma unroll
    for (int t = 0; t < QT; ++t) acc[e][t] = 0.f;

  if (o < 768) {
    int qk = (o >= 384) ? 1 : 0;
    int oo = o - qk * 384;
    int n = oo / HEADD, eb = oo % HEADD;
    const float* W = (qk ? Wk : Wq) + (size_t)n * HEADD * HEADD;
    const int ddb = n * HEADD;
    for (int d = 0; d < HEADD; ++d) {
      float4 w4 = *reinterpret_cast<const float4*>(&W[(size_t)d * HEADD + eb]);
      const float* xr = &xT[(ddb + d) * QTP];
#pragma unroll
      for (int tq = 0; tq < QT / 4; ++tq) {
        float4 xv = *reinterpret_cast<const float4*>(&xr[tq * 4]);
        float xa[4] = {xv.x, xv.y, xv.z, xv.w};
#pragma unroll
        for (int u = 0; u < 4; ++u) {
          acc[0][tq * 4 + u] += xa[u] * w4.x;
          acc[1][tq * 4 + u] += xa[u] * w4.y;
          acc[2][tq * 4 + u] += xa[u] * w4.z;
          acc[3][tq * 4 + u] += xa[u] * w4.w;
        }
      }
    }
    if (qk == 0) {
#pragma unroll
      for (int t = 0; t < QT; ++t) {
        float4 ov = {acc[0][t], acc[1][t], acc[2][t], acc[3][t]};
        *reinterpret_cast<float4*>(&q[(size_t)(t0 + t) * 384 + oo]) = ov;
      }
    } else {
#pragma unroll
      for (int t = 0; t < QT; ++t) {
        float g = gsh[t][n];
        float4 ov = {acc[0][t] * g, acc[1][t] * g, acc[2][t] * g, acc[3][t] * g};
        *reinterpret_cast<float4*>(&kg[(size_t)(t0 + t) * 384 + oo]) = ov;
      }
    }
  } else {
    int i2 = o - 768;
    int n = i2 / MEMD, eb = i2 % MEMD;
    const float* W = Wv + (size_t)n * HEADD * MEMD;
    const int ddb = n * HEADD;
    for (int d = 0; d < HEADD; ++d) {
      float4 w4 = *reinterpret_cast<const float4*>(&W[(size_t)d * MEMD + eb]);
      const float* xr = &xT[(ddb + d) * QTP];
#pragma unroll
      for (int tq = 0; tq < QT / 4; ++tq) {
        float4 xv = *reinterpret_cast<const float4*>(&xr[tq * 4]);
        float xa[4] = {xv.x, xv.y, xv.z, xv.w};
#pragma unroll
        for (int u = 0; u < 4; ++u) {
          acc[0][tq * 4 + u] += xa[u] * w4.x;
          acc[1][tq * 4 + u] += xa[u] * w4.y;
          acc[2][tq * 4 + u] += xa[u] * w4.z;
          acc[3][tq * 4 + u] += xa[u] * w4.w;
        }
      }
    }
#pragma unroll
    for (int t = 0; t < QT; ++t) {
      float4 ov = {acc[0][t], acc[1][t], acc[2][t], acc[3][t]};
      *reinterpret_cast<float4*>(&v[(size_t)(t0 + t) * 512 + i2]) = ov;
    }
  }
}

// ---------------- pass 1: per-chunk writes W[bnc][96][128] ----------------
__global__ __launch_bounds__(256) void k_memW(const float* __restrict__ kg,
                                              const float* __restrict__ v,
                                              float* __restrict__ W) {
  __shared__ float X[64 * 96];
  __shared__ float V[64 * 128];
  int bx = blockIdx.x;
  int bn = bx >> 5, ch = bx & 31;
  int b = bn >> 2, n = bn & 3;
  int t0 = b * SEQ + ch * 64;
  int tid = threadIdx.x;
  for (int i = tid; i < 64 * 96; i += 256) {
    int s = i / 96, d = i % 96;
    X[i] = kg[((size_t)(t0 + s) * NMEM + n) * HEADD + d];
  }
  for (int i = tid; i < 64 * 128; i += 256) {
    int s = i >> 7, m = i & 127;
    V[i] = v[((size_t)(t0 + s) * NMEM + n) * MEMD + m];
  }
  __syncthreads();
  float* Wb = W + (size_t)bx * 96 * 128;
  for (int t = tid; t < 768; t += 256) {
    int d0 = (t >> 5) * 4, m0 = (t & 31) * 4;
    float acc[4][4] = {};
    for (int s = 0; s < 64; ++s) {
      float4 xv = *reinterpret_cast<const float4*>(&X[s * 96 + d0]);
      float4 vv = *reinterpret_cast<const float4*>(&V[s * 128 + m0]);
      float xa[4] = {xv.x, xv.y, xv.z, xv.w};
      float va[4] = {vv.x, vv.y, vv.z, vv.w};
#pragma unroll
      for (int a = 0; a < 4; ++a)
#pragma unroll
        for (int e = 0; e < 4; ++e) acc[a][e] += xa[a] * va[e];
    }
#pragma unroll
    for (int a = 0; a < 4; ++a) {
      float4 o = {acc[a][0], acc[a][1], acc[a][2], acc[a][3]};
      *reinterpret_cast<float4*>(&Wb[(size_t)(d0 + a) * 128 + m0]) = o;
    }
  }
}

// ---------------- pass 2: prefix scan over chunks (reg-staged, fused gmean) ----
__global__ __launch_bounds__(256) void k_memscanM(const float* __restrict__ W,
                                                  const float* __restrict__ g,
                                                  float* __restrict__ Mp) {
  __shared__ float ga_sh[32];
  int bx = blockIdx.x;
  int bn = bx / 48, j = bx % 48;
  int elem = j * 256 + threadIdx.x;
  int b = bn >> 2, n = bn & 3;
  int tid = threadIdx.x;
  {
    int ch = tid >> 3, i8 = tid & 7;
    float s = 0.f;
#pragma unroll
    for (int t = 0; t < 8; ++t)
      s += g[((size_t)b * SEQ + ch * 64 + i8 * 8 + t) * NMEM + n];
#pragma unroll
    for (int o = 4; o > 0; o >>= 1) s += __shfl_down(s, o);
    if (i8 == 0) ga_sh[ch] = s * (1.0f / 64.0f);
  }
  __syncthreads();
  float wreg[32];
  size_t base0 = (size_t)bn * 32 * 12288 + elem;
#pragma unroll
  for (int ch = 0; ch < 32; ++ch) wreg[ch] = W[base0 + (size_t)ch * 12288];
  float M = 0.f;
#pragma unroll
  for (int ch = 0; ch < 32; ++ch) {
    Mp[base0 + (size_t)ch * 12288] = M;
    M = (1.f - ga_sh[ch]) * M + wreg[ch];
  }
}

// ------- pass 3: reads = q @ M_prefix, fused output projection -------
__global__ __launch_bounds__(256) void k_memR(const float* __restrict__ q,
                                              const float* __restrict__ Mp,
                                              const float* __restrict__ Wout,
                                              float* __restrict__ rdp) {
  extern __shared__ float smem[];
  float* Q = smem;
  float* Ms = smem + 64 * 96;
  int bx = blockIdx.x;
  int bn = bx >> 5, ch = bx & 31;
  int b = bn >> 2, n = bn & 3;
  int t0 = b * SEQ + ch * 64;
  int tid = threadIdx.x;
  for (int i = tid; i < 64 * 96; i += 256) {
    int s = i / 96, d = i % 96;
    Q[i] = q[((size_t)(t0 + s) * NMEM + n) * HEADD + d];
  }
  for (int i = tid; i < 96 * 128; i += 256)
    Ms[i] = Mp[((size_t)bn * 32 + ch) * 12288 + i];
  __syncthreads();
  float acc[2][4][4];
#pragma unroll
  for (int tt = 0; tt < 2; ++tt) {
    int t = tid + tt * 256;
    int s0 = (t >> 5) * 4, m0 = (t & 31) * 4;
#pragma unroll
    for (int si = 0; si < 4; ++si)
#pragma unroll
      for (int mi = 0; mi < 4; ++mi) acc[tt][si][mi] = 0.f;
    for (int k = 0; k < 96; ++k) {
      float4 mv = *reinterpret_cast<const float4*>(&Ms[k * 128 + m0]);
      float ma[4] = {mv.x, mv.y, mv.z, mv.w};
#pragma unroll
      for (int si = 0; si < 4; ++si) {
        float qs = Q[(s0 + si) * 96 + k];
#pragma unroll
        for (int mi = 0; mi < 4; ++mi) acc[tt][si][mi] += qs * ma[mi];
      }
    }
  }
  __syncthreads();  // all reads of Q/Ms done; safe to overwrite
  float* reads_s = smem;  // [64][128]
#pragma unroll
  for (int tt = 0; tt < 2; ++tt) {
    int t = tid + tt * 256;
    int s0 = (t >> 5) * 4, m0 = (t & 31) * 4;
#pragma unroll
    for (int si = 0; si < 4; ++si) {
      float4 o = {acc[tt][si][0], acc[tt][si][1], acc[tt][si][2], acc[tt][si][3]};
      *reinterpret_cast<float4*>(&reads_s[(s0 + si) * 128 + m0]) = o;
    }
  }
  __syncthreads();
  const float* Wn = Wout + (size_t)n * MEMD * HEADD;
  for (int it = tid; it < 64 * 24; it += 256) {
    int s = it / 24, c4 = (it % 24) * 4;
    float p0 = 0.f, p1 = 0.f, p2 = 0.f, p3 = 0.f;
    for (int m = 0; m < MEMD; ++m) {
      float rv = reads_s[s * 128 + m];
      float4 w4 = *reinterpret_cast<const float4*>(&Wn[(size_t)m * HEADD + c4]);
      p0 += rv * w4.x;
      p1 += rv * w4.y;
      p2 += rv * w4.z;
      p3 += rv * w4.w;
    }
    float4 o = {p0, p1, p2, p3};
    *reinterpret_cast<float4*>(
        &rdp[((size_t)(t0 + s) * NMEM + n) * HEADD + c4]) = o;
  }
}

// ---- combine (streaming): out = (hconv + rdp[mem heads]) * head_weight ----
__global__ __launch_bounds__(256) void k_combine(
    const float* __restrict__ hconv, const float* __restrict__ rdp,
    const float* __restrict__ hw, float* __restrict__ outf,
    bf16* __restrict__ outb) {
  size_t idx4 = (size_t)blockIdx.x * 256 + threadIdx.x;
  if (idx4 >= (size_t)TOKENS * HDIM / 4) return;
  size_t idx = idx4 * 4;
  int c = (int)(idx % HDIM);
  size_t tok = idx / HDIM;
  int head = c / HEADD, hd = c % HEADD;
  float4 v = *reinterpret_cast<const float4*>(&hconv[idx]);
  if (head >= 6 && head < 10) {
    float4 r = *reinterpret_cast<const float4*>(
        &rdp[((size_t)tok * NMEM + (head - 6)) * HEADD + hd]);
    v.x += r.x;
    v.y += r.y;
    v.z += r.z;
    v.w += r.w;
  }
  float w = hw[tok * NHEADS + head];
  v.x *= w;
  v.y *= w;
  v.z *= w;
  v.w *= w;
  *reinterpret_cast<float4*>(&outf[idx]) = v;
  __hip_bfloat162 p01, p23;
  p01.x = __float2bfloat16(v.x);
  p01.y = __float2bfloat16(v.y);
  p23.x = __float2bfloat16(v.z);
  p23.y = __float2bfloat16(v.w);
  *reinterpret_cast<__hip_bfloat162*>(&outb[idx]) = p01;
  *reinterpret_cast<__hip_bfloat162*>(&outb[idx + 2]) = p23;
}

extern "C" void kernel_launch(void* const* d_in, const int* in_sizes, int n_in,
                              void* d_out, int out_size, void* d_ws,
                              size_t ws_size, hipStream_t stream) {
  const float* x_in = (const float*)d_in[0];
  const float* norm1_w = (const float*)d_in[1];
  const float* norm2_w = (const float*)d_in[2];
  const float* norm3_w = (const float*)d_in[3];
  const float* cs_w = (const float*)d_in[4];
  const float* cs_b = (const float*)d_in[5];
  const float* cs_proj_w = (const float*)d_in[6];
  const float* cs_proj_b = (const float*)d_in[7];
  const float* gate_proj_w = (const float*)d_in[8];
  const float* router_w = (const float*)d_in[9];
  const float* router_b = (const float*)d_in[10];
  const float* head_w = (const float*)d_in[11];
  const float* head_b = (const float*)d_in[12];
  const float* mem_q = (const float*)d_in[13];
  const float* mem_k = (const float*)d_in[14];
  const float* mem_v = (const float*)d_in[15];
  const float* mem_gw = (const float*)d_in[16];
  const float* mem_gb = (const float*)d_in[17];
  const float* mem_out = (const float*)d_in[18];
  const float* mixgate_w = (const float*)d_in[19];
  const float* mixgate_b = (const float*)d_in[20];
  const float* mixing_w = (const float*)d_in[21];
  const float* mixing_b = (const float*)d_in[22];
  const float* ffn_in_w = (const float*)d_in[23];
  const float* ffn_out_w = (const float*)d_in[24];
  const float* cg_w = (const float*)d_in[25];
  const float* cg_b = (const float*)d_in[26];
  const float* sg_w = (const float*)d_in[27];
  const float* sg_b = (const float*)d_in[28];
  const float* fg_w = (const float*)d_in[29];
  const float* fg_b = (const float*)d_in[30];
  float* out = (float*)d_out;

  char* wsp = (char*)d_ws;
  size_t off = 0;
  auto alloc = [&](size_t bytes) -> char* {
    char* p = wsp + off;
    off += (bytes + 255) & ~(size_t)255;
    return p;
  };
  bf16* NB = (bf16*)alloc((size_t)TOKENS * HDIM * 2);
  float* F1 = (float*)alloc((size_t)TOKENS * HDIM * 4);
  float* F2 = (float*)alloc((size_t)TOKENS * HDIM * 4);
  float* F3 = (float*)alloc((size_t)TOKENS * HDIM * 4);
  char* REG = alloc((size_t)TOKENS * FINNER * 2);
  float* qb = (float*)REG;
  float* kgb = (float*)(REG + (size_t)TOKENS * 384 * 4);
  float* vb = (float*)((char*)kgb + (size_t)TOKENS * 384 * 4);
  float* rdb = (float*)((char*)vb + (size_t)TOKENS * 512 * 4);
  bf16* XG = (bf16*)REG;   // stage-C view
  bf16* NB2 = (bf16*)REG;  // mixgate output view (qb region dead by then)
  bf16* NBc = (bf16*)REG;  // conv-stack output view (stage A only)
  bf16* WTcs = (bf16*)alloc((size_t)1152 * 1152 * 2);
  bf16* WTgp = (bf16*)alloc((size_t)2304 * 1152 * 2);
  bf16* WTmg = (bf16*)alloc((size_t)1152 * 1152 * 2);
  bf16* WTmx = (bf16*)alloc((size_t)1152 * 1152 * 2);
  float* G1 = (float*)alloc(TOKENS * 4);
  float* G2 = (float*)alloc(TOKENS * 4);
  float* G3 = (float*)alloc(TOKENS * 4);
  float* GM = (float*)alloc((size_t)TOKENS * NMEM * 4);
  float* HW = (float*)alloc((size_t)TOKENS * NHEADS * 4);
  bf16* WTfin = (bf16*)F1;
  bf16* WTfout = (bf16*)F2;
  float* Wbuf = F2;
  float* Mpref = F3;

  const int gE4 = (TOKENS * HDIM) / (4 * 256);

  k_transpose_bf16<<<dim3(36, 36), 256, 0, stream>>>(cs_proj_w, WTcs, 1152, 1152);
  k_transpose_pair<<<dim3(72, 36), 256, 0, stream>>>(gate_proj_w, WTgp, 1152, 2304);
  k_transpose_bf16<<<dim3(36, 36), 256, 0, stream>>>(mixgate_w, WTmg, 1152, 1152);
  k_transpose_bf16<<<dim3(36, 36), 256, 0, stream>>>(mixing_w, WTmx, 1152, 1152);

  // ---- stage A: conv stack ----
  k_rms_gate<<<2048, 256, 0, stream>>>(x_in, norm1_w, cg_w, cg_b, NB, G1,
                                       nullptr, nullptr, nullptr);
  k_convstack<<<2304, 256, 0, stream>>>(NB, NBc, cs_w, cs_b);
  k_gemm<2><<<dim3(9, 64), 256, 0, stream>>>(NBc, WTcs, cs_proj_b, G1, x_in, out,
                                             nullptr, TOKENS, 1152, 1152);

  // ---- stage B: multi-head state ----
  k_rms_gate<<<2048, 256, 0, stream>>>(out, norm2_w, sg_w, sg_b, NB, G2,
                                       router_w, router_b, HW);
  k_gemm<4><<<dim3(18, 64), 256, 0, stream>>>(NB, WTgp, nullptr, nullptr, nullptr,
                                              F3, nullptr, TOKENS, 2304, 1152);
  k_headconv<<<gE4, 256, 0, stream>>>(F3, F1, head_w, head_b, 0);
  k_headconv<<<gE4, 256, 0, stream>>>(F1, F2, head_w, head_b, 1);
  k_headconv<<<gE4, 256, 0, stream>>>(F2, F1, head_w, head_b, 2);
  k_qkvg<<<1024, 256, 0, stream>>>(F3, mem_q, mem_k, mem_v, mem_gw, mem_gb,
                                   qb, kgb, vb, GM);
  k_memW<<<512, 256, 0, stream>>>(kgb, vb, Wbuf);
  k_memscanM<<<768, 256, 0, stream>>>(Wbuf, GM, Mpref);
  k_memR<<<512, 256, (64 * 96 + 96 * 128) * 4, stream>>>(qb, Mpref, mem_out, rdb);
  k_combine<<<gE4, 256, 0, stream>>>(F1, rdb, HW, F2, NB);
  // fused mixgate: NB2 = bf16(F2 * sigm(NB@mixgate + b))
  k_gemm<6><<<dim3(9, 64), 256, 0, stream>>>(NB, WTmg, mixgate_b, nullptr, F2,
                                             nullptr, NB2, TOKENS, 1152, 1152);
  k_gemm<2><<<dim3(9, 64), 256, 0, stream>>>(NB2, WTmx, mixing_b, G2, out, out,
                                             nullptr, TOKENS, 1152, 1152);

  // ---- stage C: GLU FFN ----
  k_rms_gate<<<2048, 256, 0, stream>>>(out, norm3_w, fg_w, fg_b, NB, G3,
                                       nullptr, nullptr, nullptr);
  k_transpose_pair<<<dim3(288, 36), 256, 0, stream>>>(ffn_in_w, WTfin, 1152, 9216);
  k_transpose_bf16<<<dim3(36, 144), 256, 0, stream>>>(ffn_out_w, WTfout, 4608, 1152);
  k_gemm<5><<<dim3(72, 64), 256, 0, stream>>>(NB, WTfin, nullptr, nullptr, nullptr,
                                              nullptr, XG, TOKENS, 9216, 1152);
  k_gemm<2><<<dim3(9, 64), 256, 0, stream>>>(XG, WTfout, nullptr, G3, out, out,
                                             nullptr, TOKENS, 1152, 4608);
}

// Round 11
// 1151.993 us; speedup vs baseline: 1.0974x; 1.0974x over previous
//
#include <hip/hip_runtime.h>
#include <hip/hip_bf16.h>
#include <math.h>

#define TOKENS 8192
#define HDIM 1152
#define SEQ 2048
#define NHEADS 12
#define HEADD 96
#define NMEM 4
#define MEMD 128
#define FINNER 4608

typedef __hip_bfloat16 bf16;
typedef __attribute__((ext_vector_type(8))) short short8;
typedef __attribute__((ext_vector_type(4))) float floatx4;

__device__ __constant__ int g_hd_dil[NHEADS * 3] = {
    1, 2, 4,   1, 1, 1,    4, 8, 16,   8, 16, 32,
    32, 64, 128, 64, 128, 256, 256, 512, 1024, 1, 100, 200,
    1, 500, 1000, 1, 1024, 2048, 3, 9, 27, 5, 25, 125};

__device__ inline float sigm(float x) { return 1.0f / (1.0f + __expf(-x)); }
__device__ inline float gelu_exact(float x) {
  return 0.5f * x * (1.0f + erff(x * 0.70710678118654752f));
}
__device__ inline float wred(float v) {
#pragma unroll
  for (int o = 32; o > 0; o >>= 1) v += __shfl_down(v, o);
  return v;
}
// async global->LDS, 16B per lane; LDS dest wave-uniform base + lane*16
__device__ inline void gl_lds16(const bf16* g, bf16* l) {
  __builtin_amdgcn_global_load_lds(
      (const __attribute__((address_space(1))) unsigned int*)g,
      (__attribute__((address_space(3))) unsigned int*)l, 16, 0, 0);
}

// ---------------- transpose f32 [K,N] -> bf16 [N,K] ----------------
__global__ __launch_bounds__(256) void k_transpose_bf16(
    const float* __restrict__ W, bf16* __restrict__ WT, int K, int N) {
  __shared__ float t[32][33];
  int k0 = blockIdx.y * 32, n0 = blockIdx.x * 32;
  int tx = threadIdx.x & 31, ty = threadIdx.x >> 5;
#pragma unroll
  for (int i = 0; i < 32; i += 8)
    t[ty + i][tx] = W[(size_t)(k0 + ty + i) * N + (n0 + tx)];
  __syncthreads();
#pragma unroll
  for (int i = 0; i < 32; i += 8)
    WT[(size_t)(n0 + ty + i) * K + (k0 + tx)] = __float2bfloat16(t[tx][ty + i]);
}

// ---- 16-col-interleaved pair transpose ----
// WT row r <- W col src(r) = (r>>5)*16 + (r&15) + ((r>>4)&1)*half.
// Within a GEMM wave, nt-even fragments hold a-cols and nt-odd the matching
// g-cols for the SAME lane -> shfl-free pair-GLU epilogue.
__global__ __launch_bounds__(256) void k_transpose_pair(
    const float* __restrict__ W, bf16* __restrict__ WT, int K, int N) {
  __shared__ float t[32][33];
  int half = N >> 1;
  int k0 = blockIdx.y * 32, n0 = blockIdx.x * 32;
  int tx = threadIdx.x & 31, ty = threadIdx.x >> 5;
  int c = (tx < 16) ? (n0 / 2 + tx) : (half + n0 / 2 + tx - 16);
#pragma unroll
  for (int i = 0; i < 32; i += 8)
    t[ty + i][tx] = W[(size_t)(k0 + ty + i) * N + c];
  __syncthreads();
#pragma unroll
  for (int i = 0; i < 32; i += 8) {
    int r = ty + i;
    WT[(size_t)(n0 + r) * K + (k0 + tx)] = __float2bfloat16(t[tx][r]);
  }
}

// ------- rmsnorm + scalar gate, wave-per-token (4 tokens/block) -------
__global__ __launch_bounds__(256) void k_rms_gate(
    const float* __restrict__ x, const float* __restrict__ nw,
    const float* __restrict__ gw, const float* __restrict__ gb,
    bf16* __restrict__ outb, float* __restrict__ gout,
    const float* __restrict__ rw, const float* __restrict__ rb,
    float* __restrict__ hwout) {
  int wave = threadIdx.x >> 6, lane = threadIdx.x & 63;
  int tok = blockIdx.x * 4 + wave;
  const float* row = x + (size_t)tok * HDIM;
  float2 a[9];
  float s2 = 0.f, gd = 0.f;
#pragma unroll
  for (int p = 0; p < 9; ++p) {
    int i2 = lane + 64 * p;
    a[p] = *reinterpret_cast<const float2*>(&row[i2 * 2]);
    float2 g2 = *reinterpret_cast<const float2*>(&gw[i2 * 2]);
    s2 += a[p].x * a[p].x + a[p].y * a[p].y;
    gd += a[p].x * g2.x + a[p].y * g2.y;
  }
  s2 = wred(s2);
  gd = wred(gd);
  if (lane == 0) gout[tok] = sigm(gd + gb[0]);
  s2 = __shfl(s2, 0);
  float rn = 1.0f / sqrtf(s2 / (float)HDIM + 1e-6f);
  float racc[NHEADS];
#pragma unroll
  for (int o = 0; o < NHEADS; ++o) racc[o] = 0.f;
#pragma unroll
  for (int p = 0; p < 9; ++p) {
    int i2 = lane + 64 * p;
    float2 w2 = *reinterpret_cast<const float2*>(&nw[i2 * 2]);
    float nx = a[p].x * rn * w2.x;
    float ny = a[p].y * rn * w2.y;
    __hip_bfloat162 pr;
    pr.x = __float2bfloat16(nx);
    pr.y = __float2bfloat16(ny);
    *reinterpret_cast<__hip_bfloat162*>(&outb[(size_t)tok * HDIM + i2 * 2]) = pr;
    if (hwout) {
      const float4* rp4 =
          reinterpret_cast<const float4*>(&rw[(size_t)(i2 * 2) * NHEADS]);
      float4 r0 = rp4[0], r1 = rp4[1], r2 = rp4[2];
      float4 r3 = rp4[3], r4 = rp4[4], r5 = rp4[5];
      racc[0] += nx * r0.x + ny * r3.x;
      racc[1] += nx * r0.y + ny * r3.y;
      racc[2] += nx * r0.z + ny * r3.z;
      racc[3] += nx * r0.w + ny * r3.w;
      racc[4] += nx * r1.x + ny * r4.x;
      racc[5] += nx * r1.y + ny * r4.y;
      racc[6] += nx * r1.z + ny * r4.z;
      racc[7] += nx * r1.w + ny * r4.w;
      racc[8] += nx * r2.x + ny * r5.x;
      racc[9] += nx * r2.y + ny * r5.y;
      racc[10] += nx * r2.z + ny * r5.z;
      racc[11] += nx * r2.w + ny * r5.w;
    }
  }
  if (hwout) {
#pragma unroll
    for (int o = 0; o < NHEADS; ++o) {
      float r = wred(racc[o]);
      if (lane == 0) hwout[(size_t)tok * NHEADS + o] = sigm(r + rb[o]);
    }
  }
}

// ---------------- fused conv stack: 6 stages, single LDS buffer ----------------
// Channel-pair per thread: float2 LDS reads/writes (halves LDS instr count).
#define CS_T 256
#define CS_HALO 189
#define CS_ROWS 445
#define CS_J2 14
__global__ __launch_bounds__(256) void k_convstack(
    const bf16* __restrict__ hin, bf16* __restrict__ outb,
    const float* __restrict__ cw, const float* __restrict__ cb) {
  __shared__ float cur[CS_ROWS * 16];
  int bx = blockIdx.x;
  int cs = bx % 72;
  int tile = (bx / 72) & 7;
  int b = bx / 576;
  int c0 = cs * 16;
  int S0 = tile * CS_T;
  int tid = threadIdx.x;
  int c4 = tid & 7, pg = tid >> 3;  // channel pair 2*c4, row-group of 32
  for (int i = tid; i < CS_ROWS * 8; i += 256) {
    int p = i >> 3, cc2 = (i & 7) * 2;
    int sg = S0 - CS_HALO + p;
    if (sg >= 0) {
      unsigned int u = *reinterpret_cast<const unsigned int*>(
          &hin[((size_t)(b * SEQ + sg)) * HDIM + c0 + cc2]);
      cur[p * 16 + cc2] = __uint_as_float(u << 16);
      cur[p * 16 + cc2 + 1] = __uint_as_float(u & 0xffff0000u);
    } else {
      cur[p * 16 + cc2] = 0.f;
      cur[p * 16 + cc2 + 1] = 0.f;
    }
  }
  const int dil[6] = {1, 2, 4, 8, 16, 32};
  const int Nk[6] = {3, 9, 21, 45, 93, 189};
  float2 nv[CS_J2];
#pragma unroll
  for (int k = 0; k < 6; ++k) {
    int dd = dil[k] * 16;
    const float4* wp = reinterpret_cast<const float4*>(
        &cw[((size_t)k * HDIM + c0 + c4 * 2) * 4]);
    float4 wA = wp[0], wB = wp[1];
    float2 bb = *reinterpret_cast<const float2*>(&cb[(size_t)k * HDIM + c0 + c4 * 2]);
    __syncthreads();
#pragma unroll
    for (int j = 0; j < CS_J2; ++j) {
      int p = pg + 32 * j;
      if (p >= Nk[k] && p < CS_ROWS) {
        int i = p * 16 + c4 * 2;
        float2 t3 = *reinterpret_cast<const float2*>(&cur[i - 3 * dd]);
        float2 t2 = *reinterpret_cast<const float2*>(&cur[i - 2 * dd]);
        float2 t1 = *reinterpret_cast<const float2*>(&cur[i - dd]);
        float2 t0 = *reinterpret_cast<const float2*>(&cur[i]);
        float acc0 = bb.x + wA.x * t3.x + wA.y * t2.x + wA.z * t1.x + wA.w * t0.x;
        float acc1 = bb.y + wB.x * t3.y + wB.y * t2.y + wB.z * t1.y + wB.w * t0.y;
        int sg = S0 - CS_HALO + p;
        if (sg >= 0) {
          nv[j].x = t0.x + gelu_exact(acc0);
          nv[j].y = t0.y + gelu_exact(acc1);
        } else {
          nv[j].x = 0.f;
          nv[j].y = 0.f;
        }
      }
    }
    __syncthreads();
#pragma unroll
    for (int j = 0; j < CS_J2; ++j) {
      int p = pg + 32 * j;
      if (p >= Nk[k] && p < CS_ROWS)
        *reinterpret_cast<float2*>(&cur[p * 16 + c4 * 2]) = nv[j];
    }
  }
  __syncthreads();
  for (int r = pg; r < CS_T; r += 32) {
    float2 v2 = *reinterpret_cast<const float2*>(&cur[(CS_HALO + r) * 16 + c4 * 2]);
    __hip_bfloat162 pr;
    pr.x = __float2bfloat16(v2.x);
    pr.y = __float2bfloat16(v2.y);
    *reinterpret_cast<__hip_bfloat162*>(
        &outb[((size_t)(b * SEQ + S0 + r)) * HDIM + c0 + c4 * 2]) = pr;
  }
}

// ------- fused per-head conv (all 3 stages): full sequence in LDS -------
// block = (batch, 4-channel group); LDS cur[2048][6] (4 ch + 2 pad) = 48KB.
// Stride 6 keeps float2 8B-aligned with <=2-way bank aliasing (free).
// Each stage: compute 16 positions/thread into regs, barrier, write back.
// Replaces 3 streaming passes (226MB HBM) with one (75MB + L3 hits).
#define HC_S 6
__global__ __launch_bounds__(256) void k_headconv3(
    const float* __restrict__ hin, float* __restrict__ hout,
    const float* __restrict__ hw_, const float* __restrict__ hb_) {
  __shared__ float cur[SEQ * HC_S];
  int bx = blockIdx.x;
  int b = bx / 288;
  int grp = bx % 288;
  int c0 = grp * 4;
  int head = c0 / HEADD;
  int hd0 = c0 % HEADD;
  int tid = threadIdx.x;
  int pr = tid & 1, rg = tid >> 1;  // pair pr: channels c0+2pr, c0+2pr+1
  for (int i = tid; i < SEQ * 2; i += 256) {
    int s = i >> 1, pp = i & 1;
    float2 v = *reinterpret_cast<const float2*>(
        &hin[((size_t)(b * SEQ + s)) * HDIM + c0 + pp * 2]);
    *reinterpret_cast<float2*>(&cur[s * HC_S + pp * 2]) = v;
  }
  float2 nv[16];
#pragma unroll
  for (int j = 0; j < 3; ++j) {
    int d = g_hd_dil[head * 3 + j];
    const float4* wp = reinterpret_cast<const float4*>(
        &hw_[((size_t)(head * 3 + j) * HEADD + hd0 + pr * 2) * 4]);
    float4 wA = wp[0], wB = wp[1];  // taps (back 3d,2d,d,0) for the 2 channels
    float2 bb = *reinterpret_cast<const float2*>(
        &hb_[(size_t)(head * 3 + j) * HEADD + hd0 + pr * 2]);
    __syncthreads();
#pragma unroll
    for (int jj = 0; jj < 16; ++jj) {
      int p = rg + 128 * jj;
      float2 t0 = *reinterpret_cast<const float2*>(&cur[p * HC_S + pr * 2]);
      float a0 = bb.x + wA.w * t0.x;
      float a1 = bb.y + wB.w * t0.y;
      if (p - d >= 0) {
        float2 t = *reinterpret_cast<const float2*>(&cur[(p - d) * HC_S + pr * 2]);
        a0 += wA.z * t.x;
        a1 += wB.z * t.y;
      }
      if (p - 2 * d >= 0) {
        float2 t = *reinterpret_cast<const float2*>(&cur[(p - 2 * d) * HC_S + pr * 2]);
        a0 += wA.y * t.x;
        a1 += wB.y * t.y;
      }
      if (p - 3 * d >= 0) {
        float2 t = *reinterpret_cast<const float2*>(&cur[(p - 3 * d) * HC_S + pr * 2]);
        a0 += wA.x * t.x;
        a1 += wB.x * t.y;
      }
      nv[jj].x = t0.x + a0;
      nv[jj].y = t0.y + a1;
    }
    __syncthreads();
#pragma unroll
    for (int jj = 0; jj < 16; ++jj) {
      int p = rg + 128 * jj;
      *reinterpret_cast<float2*>(&cur[p * HC_S + pr * 2]) = nv[jj];
    }
  }
  __syncthreads();
  for (int i = tid; i < SEQ * 2; i += 256) {
    int s = i >> 1, pp = i & 1;
    float2 v = *reinterpret_cast<const float2*>(&cur[s * HC_S + pp * 2]);
    *reinterpret_cast<float2*>(
        &hout[((size_t)(b * SEQ + s)) * HDIM + c0 + pp * 2]) = v;
  }
}

// ---------------- GEMM: BK=64, global_load_lds staging, swizzled LDS ----------
// MODE 2: out = addin + gate[m]*(acc+bias)
// MODE 4: pair-GLU -> a*sigm(g) f32 (16-col-interleaved WT; shfl-free)
// MODE 5: pair-GLU -> bf16 (same)
// MODE 6: outb = bf16(addin * sigm(acc+bias))
template <int MODE>
__global__ __launch_bounds__(256) void k_gemm(
    const bf16* __restrict__ A, const bf16* __restrict__ BT,
    const float* __restrict__ bias, const float* __restrict__ gate,
    const float* addin, float* outf, bf16* outb, int M, int N, int K) {
  __shared__ bf16 As[128 * 64];
  __shared__ bf16 Bs[128 * 64];
  const int tid = threadIdx.x;
  const int m0 = blockIdx.y * 128, n0 = blockIdx.x * 128;
  const int wave = tid >> 6, lane = tid & 63;
  const int wm = (wave & 1) * 64, wn = (wave >> 1) * 64;
  const int l16 = lane & 15, kq = lane >> 4;
  const int srow = lane >> 3;
  const int schunk = ((lane & 7) - srow) & 7;
  const bf16* gA = A + (size_t)(m0 + wave * 32 + srow) * K + schunk * 8;
  const bf16* gB = BT + (size_t)(n0 + wave * 32 + srow) * K + schunk * 8;
  bf16* lA = &As[wave * 32 * 64];
  bf16* lB = &Bs[wave * 32 * 64];
  const size_t rstride = (size_t)8 * K;
  const int col0 = ((kq + l16) & 7) * 8;
  const int col1 = ((kq + 4 + l16) & 7) * 8;
  floatx4 acc[4][4];
  floatx4 zero = {0.f, 0.f, 0.f, 0.f};
#pragma unroll
  for (int i = 0; i < 4; ++i)
#pragma unroll
    for (int jj = 0; jj < 4; ++jj) acc[i][jj] = zero;

  for (int k0 = 0; k0 < K; k0 += 64) {
    __syncthreads();
#pragma unroll
    for (int i = 0; i < 4; ++i) {
      gl_lds16(gA + k0 + i * rstride, lA + i * 8 * 64);
      gl_lds16(gB + k0 + i * rstride, lB + i * 8 * 64);
    }
    __syncthreads();
#pragma unroll
    for (int ks = 0; ks < 2; ++ks) {
      const int col = ks ? col1 : col0;
      short8 af[4], bfr[4];
#pragma unroll
      for (int t = 0; t < 4; ++t) {
        af[t] = *reinterpret_cast<const short8*>(&As[(wm + t * 16 + l16) * 64 + col]);
        bfr[t] = *reinterpret_cast<const short8*>(&Bs[(wn + t * 16 + l16) * 64 + col]);
      }
#pragma unroll
      for (int mt = 0; mt < 4; ++mt)
#pragma unroll
        for (int nt = 0; nt < 4; ++nt)
          acc[mt][nt] = __builtin_amdgcn_mfma_f32_16x16x32_bf16(
              af[mt], bfr[nt], acc[mt][nt], 0, 0, 0);
    }
  }

  if (MODE == 4 || MODE == 5) {
    const int halfN = N >> 1;
    // nt even holds a, nt odd holds g for the SAME lane (16-col interleave).
#pragma unroll
    for (int mt = 0; mt < 4; ++mt) {
#pragma unroll
      for (int ntp = 0; ntp < 2; ++ntp) {
        int cc = ((n0 + wn) >> 1) + ntp * 16 + l16;
#pragma unroll
        for (int r = 0; r < 4; ++r) {
          float a = acc[mt][ntp * 2][r];
          float g = acc[mt][ntp * 2 + 1][r];
          int m = m0 + wm + mt * 16 + kq * 4 + r;
          float res = a * sigm(g);
          size_t o = (size_t)m * halfN + cc;
          if (MODE == 4) outf[o] = res;
          else outb[o] = __float2bfloat16(res);
        }
      }
    }
    return;
  }

#pragma unroll
  for (int mt = 0; mt < 4; ++mt) {
#pragma unroll
    for (int nt = 0; nt < 4; ++nt) {
      int n = n0 + wn + nt * 16 + l16;
      float bv = bias ? bias[n] : 0.f;
#pragma unroll
      for (int r = 0; r < 4; ++r) {
        int m = m0 + wm + mt * 16 + kq * 4 + r;
        float v = acc[mt][nt][r] + bv;
        size_t o = (size_t)m * N + n;
        if (MODE == 2) outf[o] = addin[o] + gate[m] * v;
        else if (MODE == 6) outb[o] = __float2bfloat16(addin[o] * sigm(v));
      }
    }
  }
}

// -------- memory q/kg/v/g projections: token-tiled, register-blocked --------
#define QT 16
#define QTP 20  // padded LDS stride
__global__ __launch_bounds__(256) void k_qkvg(
    const float* __restrict__ xh, const float* __restrict__ Wq,
    const float* __restrict__ Wk, const float* __restrict__ Wv,
    const float* __restrict__ gw, const float* __restrict__ gb,
    float* __restrict__ q, float* __restrict__ kg, float* __restrict__ v,
    float* __restrict__ gout) {
  __shared__ float xT[384 * QTP];  // xT[dd*QTP + t]
  __shared__ float gsh[QT][NMEM];
  int bx = blockIdx.x;
  int grp = bx & 1;
  int tile = bx >> 1;
  int t0 = tile * QT;
  int tid = threadIdx.x;
  for (int i = tid; i < 384 * QT; i += 256) {
    int t = i / 384, dd = i % 384;
    xT[dd * QTP + t] = xh[(size_t)(t0 + t) * HDIM + 6 * HEADD + dd];
  }
  __syncthreads();
  if (grp == 0) {
    if (tid < 64) {
      int t = tid >> 2, n = tid & 3;
      float a = gb[n];
      for (int d = 0; d < HEADD; ++d)
        a += xT[(n * HEADD + d) * QTP + t] * gw[n * HEADD + d];
      float s = sigm(a);
      gsh[t][n] = s;
      gout[(size_t)(t0 + t) * NMEM + n] = s;
    }
    __syncthreads();
  }
  int o = grp * 1024 + tid * 4;
  if (o >= 1280) return;
  float acc[4][QT];
#pragma unroll
  for (int e = 0; e < 4; ++e)
#pragma unroll
    for (int t = 0; t < QT; ++t) acc[e][t] = 0.f;

  if (o < 768) {
    int qk = (o >= 384) ? 1 : 0;
    int oo = o - qk * 384;
    int n = oo / HEADD, eb = oo % HEADD;
    const float* W = (qk ? Wk : Wq) + (size_t)n * HEADD * HEADD;
    const int ddb = n * HEADD;
    for (int d = 0; d < HEADD; ++d) {
      float4 w4 = *reinterpret_cast<const float4*>(&W[(size_t)d * HEADD + eb]);
      const float* xr = &xT[(ddb + d) * QTP];
#pragma unroll
      for (int tq = 0; tq < QT / 4; ++tq) {
        float4 xv = *reinterpret_cast<const float4*>(&xr[tq * 4]);
        float xa[4] = {xv.x, xv.y, xv.z, xv.w};
#pragma unroll
        for (int u = 0; u < 4; ++u) {
          acc[0][tq * 4 + u] += xa[u] * w4.x;
          acc[1][tq * 4 + u] += xa[u] * w4.y;
          acc[2][tq * 4 + u] += xa[u] * w4.z;
          acc[3][tq * 4 + u] += xa[u] * w4.w;
        }
      }
    }
    if (qk == 0) {
#pragma unroll
      for (int t = 0; t < QT; ++t) {
        float4 ov = {acc[0][t], acc[1][t], acc[2][t], acc[3][t]};
        *reinterpret_cast<float4*>(&q[(size_t)(t0 + t) * 384 + oo]) = ov;
      }
    } else {
#pragma unroll
      for (int t = 0; t < QT; ++t) {
        float g = gsh[t][n];
        float4 ov = {acc[0][t] * g, acc[1][t] * g, acc[2][t] * g, acc[3][t] * g};
        *reinterpret_cast<float4*>(&kg[(size_t)(t0 + t) * 384 + oo]) = ov;
      }
    }
  } else {
    int i2 = o - 768;
    int n = i2 / MEMD, eb = i2 % MEMD;
    const float* W = Wv + (size_t)n * HEADD * MEMD;
    const int ddb = n * HEADD;
    for (int d = 0; d < HEADD; ++d) {
      float4 w4 = *reinterpret_cast<const float4*>(&W[(size_t)d * MEMD + eb]);
      const float* xr = &xT[(ddb + d) * QTP];
#pragma unroll
      for (int tq = 0; tq < QT / 4; ++tq) {
        float4 xv = *reinterpret_cast<const float4*>(&xr[tq * 4]);
        float xa[4] = {xv.x, xv.y, xv.z, xv.w};
#pragma unroll
        for (int u = 0; u < 4; ++u) {
          acc[0][tq * 4 + u] += xa[u] * w4.x;
          acc[1][tq * 4 + u] += xa[u] * w4.y;
          acc[2][tq * 4 + u] += xa[u] * w4.z;
          acc[3][tq * 4 + u] += xa[u] * w4.w;
        }
      }
    }
#pragma unroll
    for (int t = 0; t < QT; ++t) {
      float4 ov = {acc[0][t], acc[1][t], acc[2][t], acc[3][t]};
      *reinterpret_cast<float4*>(&v[(size_t)(t0 + t) * 512 + i2]) = ov;
    }
  }
}

// ---------------- pass 1: per-chunk writes W[bnc][96][128] ----------------
__global__ __launch_bounds__(256) void k_memW(const float* __restrict__ kg,
                                              const float* __restrict__ v,
                                              float* __restrict__ W) {
  __shared__ float X[64 * 96];
  __shared__ float V[64 * 128];
  int bx = blockIdx.x;
  int bn = bx >> 5, ch = bx & 31;
  int b = bn >> 2, n = bn & 3;
  int t0 = b * SEQ + ch * 64;
  int tid = threadIdx.x;
  for (int i = tid; i < 64 * 96; i += 256) {
    int s = i / 96, d = i % 96;
    X[i] = kg[((size_t)(t0 + s) * NMEM + n) * HEADD + d];
  }
  for (int i = tid; i < 64 * 128; i += 256) {
    int s = i >> 7, m = i & 127;
    V[i] = v[((size_t)(t0 + s) * NMEM + n) * MEMD + m];
  }
  __syncthreads();
  float* Wb = W + (size_t)bx * 96 * 128;
  for (int t = tid; t < 768; t += 256) {
    int d0 = (t >> 5) * 4, m0 = (t & 31) * 4;
    float acc[4][4] = {};
    for (int s = 0; s < 64; ++s) {
      float4 xv = *reinterpret_cast<const float4*>(&X[s * 96 + d0]);
      float4 vv = *reinterpret_cast<const float4*>(&V[s * 128 + m0]);
      float xa[4] = {xv.x, xv.y, xv.z, xv.w};
      float va[4] = {vv.x, vv.y, vv.z, vv.w};
#pragma unroll
      for (int a = 0; a < 4; ++a)
#pragma unroll
        for (int e = 0; e < 4; ++e) acc[a][e] += xa[a] * va[e];
    }
#pragma unroll
    for (int a = 0; a < 4; ++a) {
      float4 o = {acc[a][0], acc[a][1], acc[a][2], acc[a][3]};
      *reinterpret_cast<float4*>(&Wb[(size_t)(d0 + a) * 128 + m0]) = o;
    }
  }
}

// ---------------- pass 2: prefix scan over chunks (reg-staged, fused gmean) ----
__global__ __launch_bounds__(256) void k_memscanM(const float* __restrict__ W,
                                                  const float* __restrict__ g,
                                                  float* __restrict__ Mp) {
  __shared__ float ga_sh[32];
  int bx = blockIdx.x;
  int bn = bx / 48, j = bx % 48;
  int elem = j * 256 + threadIdx.x;
  int b = bn >> 2, n = bn & 3;
  int tid = threadIdx.x;
  {
    int ch = tid >> 3, i8 = tid & 7;
    float s = 0.f;
#pragma unroll
    for (int t = 0; t < 8; ++t)
      s += g[((size_t)b * SEQ + ch * 64 + i8 * 8 + t) * NMEM + n];
#pragma unroll
    for (int o = 4; o > 0; o >>= 1) s += __shfl_down(s, o);
    if (i8 == 0) ga_sh[ch] = s * (1.0f / 64.0f);
  }
  __syncthreads();
  float wreg[32];
  size_t base0 = (size_t)bn * 32 * 12288 + elem;
#pragma unroll
  for (int ch = 0; ch < 32; ++ch) wreg[ch] = W[base0 + (size_t)ch * 12288];
  float M = 0.f;
#pragma unroll
  for (int ch = 0; ch < 32; ++ch) {
    Mp[base0 + (size_t)ch * 12288] = M;
    M = (1.f - ga_sh[ch]) * M + wreg[ch];
  }
}

// ------- pass 3: reads = q @ M_prefix, fused output projection -------
__global__ __launch_bounds__(256) void k_memR(const float* __restrict__ q,
                                              const float* __restrict__ Mp,
                                              const float* __restrict__ Wout,
                                              float* __restrict__ rdp) {
  extern __shared__ float smem[];
  float* Q = smem;
  float* Ms = smem + 64 * 96;
  int bx = blockIdx.x;
  int bn = bx >> 5, ch = bx & 31;
  int b = bn >> 2, n = bn & 3;
  int t0 = b * SEQ + ch * 64;
  int tid = threadIdx.x;
  for (int i = tid; i < 64 * 96; i += 256) {
    int s = i / 96, d = i % 96;
    Q[i] = q[((size_t)(t0 + s) * NMEM + n) * HEADD + d];
  }
  for (int i = tid; i < 96 * 128; i += 256)
    Ms[i] = Mp[((size_t)bn * 32 + ch) * 12288 + i];
  __syncthreads();
  float acc[2][4][4];
#pragma unroll
  for (int tt = 0; tt < 2; ++tt) {
    int t = tid + tt * 256;
    int s0 = (t >> 5) * 4, m0 = (t & 31) * 4;
#pragma unroll
    for (int si = 0; si < 4; ++si)
#pragma unroll
      for (int mi = 0; mi < 4; ++mi) acc[tt][si][mi] = 0.f;
    for (int k = 0; k < 96; ++k) {
      float4 mv = *reinterpret_cast<const float4*>(&Ms[k * 128 + m0]);
      float ma[4] = {mv.x, mv.y, mv.z, mv.w};
#pragma unroll
      for (int si = 0; si < 4; ++si) {
        float qs = Q[(s0 + si) * 96 + k];
#pragma unroll
        for (int mi = 0; mi < 4; ++mi) acc[tt][si][mi] += qs * ma[mi];
      }
    }
  }
  __syncthreads();  // all reads of Q/Ms done; safe to overwrite
  float* reads_s = smem;  // [64][128]
#pragma unroll
  for (int tt = 0; tt < 2; ++tt) {
    int t = tid + tt * 256;
    int s0 = (t >> 5) * 4, m0 = (t & 31) * 4;
#pragma unroll
    for (int si = 0; si < 4; ++si) {
      float4 o = {acc[tt][si][0], acc[tt][si][1], acc[tt][si][2], acc[tt][si][3]};
      *reinterpret_cast<float4*>(&reads_s[(s0 + si) * 128 + m0]) = o;
    }
  }
  __syncthreads();
  const float* Wn = Wout + (size_t)n * MEMD * HEADD;
  for (int it = tid; it < 64 * 24; it += 256) {
    int s = it / 24, c4 = (it % 24) * 4;
    float p0 = 0.f, p1 = 0.f, p2 = 0.f, p3 = 0.f;
    for (int m = 0; m < MEMD; ++m) {
      float rv = reads_s[s * 128 + m];
      float4 w4 = *reinterpret_cast<const float4*>(&Wn[(size_t)m * HEADD + c4]);
      p0 += rv * w4.x;
      p1 += rv * w4.y;
      p2 += rv * w4.z;
      p3 += rv * w4.w;
    }
    float4 o = {p0, p1, p2, p3};
    *reinterpret_cast<float4*>(
        &rdp[((size_t)(t0 + s) * NMEM + n) * HEADD + c4]) = o;
  }
}

// ---- combine (streaming): out = (hconv + rdp[mem heads]) * head_weight ----
__global__ __launch_bounds__(256) void k_combine(
    const float* __restrict__ hconv, const float* __restrict__ rdp,
    const float* __restrict__ hw, float* __restrict__ outf,
    bf16* __restrict__ outb) {
  size_t idx4 = (size_t)blockIdx.x * 256 + threadIdx.x;
  if (idx4 >= (size_t)TOKENS * HDIM / 4) return;
  size_t idx = idx4 * 4;
  int c = (int)(idx % HDIM);
  size_t tok = idx / HDIM;
  int head = c / HEADD, hd = c % HEADD;
  float4 v = *reinterpret_cast<const float4*>(&hconv[idx]);
  if (head >= 6 && head < 10) {
    float4 r = *reinterpret_cast<const float4*>(
        &rdp[((size_t)tok * NMEM + (head - 6)) * HEADD + hd]);
    v.x += r.x;
    v.y += r.y;
    v.z += r.z;
    v.w += r.w;
  }
  float w = hw[tok * NHEADS + head];
  v.x *= w;
  v.y *= w;
  v.z *= w;
  v.w *= w;
  *reinterpret_cast<float4*>(&outf[idx]) = v;
  __hip_bfloat162 p01, p23;
  p01.x = __float2bfloat16(v.x);
  p01.y = __float2bfloat16(v.y);
  p23.x = __float2bfloat16(v.z);
  p23.y = __float2bfloat16(v.w);
  *reinterpret_cast<__hip_bfloat162*>(&outb[idx]) = p01;
  *reinterpret_cast<__hip_bfloat162*>(&outb[idx + 2]) = p23;
}

extern "C" void kernel_launch(void* const* d_in, const int* in_sizes, int n_in,
                              void* d_out, int out_size, void* d_ws,
                              size_t ws_size, hipStream_t stream) {
  const float* x_in = (const float*)d_in[0];
  const float* norm1_w = (const float*)d_in[1];
  const float* norm2_w = (const float*)d_in[2];
  const float* norm3_w = (const float*)d_in[3];
  const float* cs_w = (const float*)d_in[4];
  const float* cs_b = (const float*)d_in[5];
  const float* cs_proj_w = (const float*)d_in[6];
  const float* cs_proj_b = (const float*)d_in[7];
  const float* gate_proj_w = (const float*)d_in[8];
  const float* router_w = (const float*)d_in[9];
  const float* router_b = (const float*)d_in[10];
  const float* head_w = (const float*)d_in[11];
  const float* head_b = (const float*)d_in[12];
  const float* mem_q = (const float*)d_in[13];
  const float* mem_k = (const float*)d_in[14];
  const float* mem_v = (const float*)d_in[15];
  const float* mem_gw = (const float*)d_in[16];
  const float* mem_gb = (const float*)d_in[17];
  const float* mem_out = (const float*)d_in[18];
  const float* mixgate_w = (const float*)d_in[19];
  const float* mixgate_b = (const float*)d_in[20];
  const float* mixing_w = (const float*)d_in[21];
  const float* mixing_b = (const float*)d_in[22];
  const float* ffn_in_w = (const float*)d_in[23];
  const float* ffn_out_w = (const float*)d_in[24];
  const float* cg_w = (const float*)d_in[25];
  const float* cg_b = (const float*)d_in[26];
  const float* sg_w = (const float*)d_in[27];
  const float* sg_b = (const float*)d_in[28];
  const float* fg_w = (const float*)d_in[29];
  const float* fg_b = (const float*)d_in[30];
  float* out = (float*)d_out;

  char* wsp = (char*)d_ws;
  size_t off = 0;
  auto alloc = [&](size_t bytes) -> char* {
    char* p = wsp + off;
    off += (bytes + 255) & ~(size_t)255;
    return p;
  };
  bf16* NB = (bf16*)alloc((size_t)TOKENS * HDIM * 2);
  float* F1 = (float*)alloc((size_t)TOKENS * HDIM * 4);
  float* F2 = (float*)alloc((size_t)TOKENS * HDIM * 4);
  float* F3 = (float*)alloc((size_t)TOKENS * HDIM * 4);
  char* REG = alloc((size_t)TOKENS * FINNER * 2);
  float* qb = (float*)REG;
  float* kgb = (float*)(REG + (size_t)TOKENS * 384 * 4);
  float* vb = (float*)((char*)kgb + (size_t)TOKENS * 384 * 4);
  float* rdb = (float*)((char*)vb + (size_t)TOKENS * 512 * 4);
  bf16* XG = (bf16*)REG;   // stage-C view
  bf16* NB2 = (bf16*)REG;  // mixgate output view (qb region dead by then)
  bf16* NBc = (bf16*)REG;  // conv-stack output view (stage A only)
  bf16* WTcs = (bf16*)alloc((size_t)1152 * 1152 * 2);
  bf16* WTgp = (bf16*)alloc((size_t)2304 * 1152 * 2);
  bf16* WTmg = (bf16*)alloc((size_t)1152 * 1152 * 2);
  bf16* WTmx = (bf16*)alloc((size_t)1152 * 1152 * 2);
  float* G1 = (float*)alloc(TOKENS * 4);
  float* G2 = (float*)alloc(TOKENS * 4);
  float* G3 = (float*)alloc(TOKENS * 4);
  float* GM = (float*)alloc((size_t)TOKENS * NMEM * 4);
  float* HW = (float*)alloc((size_t)TOKENS * NHEADS * 4);
  bf16* WTfin = (bf16*)F1;
  bf16* WTfout = (bf16*)F2;
  float* Wbuf = F2;
  float* Mpref = F3;

  const int gE4 = (TOKENS * HDIM) / (4 * 256);

  k_transpose_bf16<<<dim3(36, 36), 256, 0, stream>>>(cs_proj_w, WTcs, 1152, 1152);
  k_transpose_pair<<<dim3(72, 36), 256, 0, stream>>>(gate_proj_w, WTgp, 1152, 2304);
  k_transpose_bf16<<<dim3(36, 36), 256, 0, stream>>>(mixgate_w, WTmg, 1152, 1152);
  k_transpose_bf16<<<dim3(36, 36), 256, 0, stream>>>(mixing_w, WTmx, 1152, 1152);

  // ---- stage A: conv stack ----
  k_rms_gate<<<2048, 256, 0, stream>>>(x_in, norm1_w, cg_w, cg_b, NB, G1,
                                       nullptr, nullptr, nullptr);
  k_convstack<<<2304, 256, 0, stream>>>(NB, NBc, cs_w, cs_b);
  k_gemm<2><<<dim3(9, 64), 256, 0, stream>>>(NBc, WTcs, cs_proj_b, G1, x_in, out,
                                             nullptr, TOKENS, 1152, 1152);

  // ---- stage B: multi-head state ----
  k_rms_gate<<<2048, 256, 0, stream>>>(out, norm2_w, sg_w, sg_b, NB, G2,
                                       router_w, router_b, HW);
  k_gemm<4><<<dim3(18, 64), 256, 0, stream>>>(NB, WTgp, nullptr, nullptr, nullptr,
                                              F3, nullptr, TOKENS, 2304, 1152);
  k_headconv3<<<1152, 256, 0, stream>>>(F3, F1, head_w, head_b);
  k_qkvg<<<1024, 256, 0, stream>>>(F3, mem_q, mem_k, mem_v, mem_gw, mem_gb,
                                   qb, kgb, vb, GM);
  k_memW<<<512, 256, 0, stream>>>(kgb, vb, Wbuf);
  k_memscanM<<<768, 256, 0, stream>>>(Wbuf, GM, Mpref);
  k_memR<<<512, 256, (64 * 96 + 96 * 128) * 4, stream>>>(qb, Mpref, mem_out, rdb);
  k_combine<<<gE4, 256, 0, stream>>>(F1, rdb, HW, F2, NB);
  // fused mixgate: NB2 = bf16(F2 * sigm(NB@mixgate + b))
  k_gemm<6><<<dim3(9, 64), 256, 0, stream>>>(NB, WTmg, mixgate_b, nullptr, F2,
                                             nullptr, NB2, TOKENS, 1152, 1152);
  k_gemm<2><<<dim3(9, 64), 256, 0, stream>>>(NB2, WTmx, mixing_b, G2, out, out,
                                             nullptr, TOKENS, 1152, 1152);

  // ---- stage C: GLU FFN ----
  k_rms_gate<<<2048, 256, 0, stream>>>(out, norm3_w, fg_w, fg_b, NB, G3,
                                       nullptr, nullptr, nullptr);
  k_transpose_pair<<<dim3(288, 36), 256, 0, stream>>>(ffn_in_w, WTfin, 1152, 9216);
  k_transpose_bf16<<<dim3(36, 144), 256, 0, stream>>>(ffn_out_w, WTfout, 4608, 1152);
  k_gemm<5><<<dim3(72, 64), 256, 0, stream>>>(NB, WTfin, nullptr, nullptr, nullptr,
                                              nullptr, XG, TOKENS, 9216, 1152);
  k_gemm<2><<<dim3(9, 64), 256, 0, stream>>>(XG, WTfout, nullptr, G3, out, out,
                                             nullptr, TOKENS, 1152, 4608);
}